// Round 3
// baseline (2038.304 us; speedup 1.0000x reference)
//
#include <hip/hip_runtime.h>
#include <cstdint>
#include <cstddef>

// Problem constants
#define C_ 256
#define HW_ 4096
#define N_ 131072          // B*H*W = 32*64*64
#define K_ 1024
#define VQ_OFF   33554432  // after z_q (32*256*64*64)
#define IDX_OFF  33554433
#define TOPO_OFF 33685505  // IDX_OFF + 131072
#define VQ_SCALE (1.25f / 33554432.0f)   // (1+0.25) * mean over B*H*W*C elements
#define REFINE_TAU 4e-3f   // unnormalized-dot gap below which we np-emulate (fp32 err << this)
#define MARK 2048          // idx marker for flagged pixels (true idx < 1024)
#define QCAP 256

// fp32 multiply with an anti-contraction barrier: numpy rounds x*x BEFORE the
// pairwise add; default -ffp-contract would fuse mul+add into fma (different rounding).
__device__ __forceinline__ float mul_nofuse(float a, float b) {
    float t = a * b;
    asm volatile("" : "+v"(t));
    return t;
}

// numpy pairwise_sum of squares, n=128 (8-accumulator unroll, numpy combine order)
__device__ __forceinline__ float np_sumsq128(const float* x) {
    float r[8];
    #pragma unroll
    for (int j = 0; j < 8; j++) r[j] = mul_nofuse(x[j], x[j]);
    for (int i = 8; i < 128; i += 8) {
        #pragma unroll
        for (int j = 0; j < 8; j++) r[j] += mul_nofuse(x[i + j], x[i + j]);
    }
    return ((r[0] + r[1]) + (r[2] + r[3])) + ((r[4] + r[5]) + (r[6] + r[7]));
}

// numpy-emulated ||x|| for 256 contiguous floats: pairwise(256) = pw(128)+pw(128)
__device__ __forceinline__ float np_norm256(const float* x) {
    float ss = np_sumsq128(x) + np_sumsq128(x + 128);
    return sqrtf(ss);
}

__global__ void k_init(float* __restrict__ out) {
    if (threadIdx.x == 0) {
        out[VQ_OFF] = 0.0f;
        out[TOPO_OFF] = 0.0f;
    }
}

// Normalize codebook rows with numpy-emulated norms; store transposed wT[c][k].
// One thread per row (4 blocks x 256 threads).
__global__ void k_normw(const float* __restrict__ w, float* __restrict__ wT) {
    int r = (blockIdx.x << 8) + threadIdx.x;
    const float* x = w + ((size_t)r << 8);
    float nrm = fmaxf(np_norm256(x), 1e-12f);
    for (int c = 0; c < C_; c++)
        wT[(c << 10) + r] = x[c] / nrm;     // wave lockstep over c -> coalesced stores
}

// Topology smoothness loss over the 32x32 grid of normalized codewords.
__global__ void k_topo(const float* __restrict__ wT, float* __restrict__ out) {
    const float W12 = 0.35f / (32.0f * 31.0f * 256.0f);
    const float W34 = 0.35f / (32.0f * 256.0f);
    float acc = 0.0f;
    int base = (blockIdx.x << 8) + threadIdx.x;
    #pragma unroll
    for (int i = 0; i < 4; i++) {
        int e = base + (i << 16);      // e = c*1024 + k, coalesced over wT
        int k = e & 1023;
        int ii = k >> 5, jj = k & 31;
        float v = wT[e];
        if (jj < 31)  { float d = wT[e + 1]   - v; acc += d * d * W12; }
        if (ii < 31)  { float d = wT[e + 32]  - v; acc += d * d * W12; }
        if (jj == 31) { float d = wT[e - 31]  - v; acc += d * d * W34; }   // w[i][0]-w[i][31]
        if (ii == 31) { float d = wT[e - 992] - v; acc += d * d * W34; }   // w[0][j]-w[31][j]
    }
    for (int off = 32; off > 0; off >>= 1) acc += __shfl_xor(acc, off);
    __shared__ float red[4];
    if ((threadIdx.x & 63) == 0) red[threadIdx.x >> 6] = acc;
    __syncthreads();
    if (threadIdx.x == 0) atomicAdd(out + TOPO_OFF, red[0] + red[1] + red[2] + red[3]);
}

// Main: per block, 64 pixels staged in LDS; 4 waves each scan 256 codewords.
// Near-tie pixels get idx tagged +MARK for the numpy-emulation refine pass.
__global__ __launch_bounds__(256, 2)
void k_main(const float* __restrict__ z, const float* __restrict__ wT,
            float* __restrict__ out) {
    __shared__ float a_lds[C_][64];
    __shared__ float m_v[4][64];
    __shared__ float m_s[4][64];
    __shared__ int   m_i[4][64];

    int tid = threadIdx.x;
    int pb  = blockIdx.x;          // pixel block: 64 consecutive pixels
    int b   = pb >> 6;             // image index
    int hwb = (pb & 63) << 6;      // base flat hw within the 64x64 plane

    const float4* src = reinterpret_cast<const float4*>(z + ((size_t)b << 20) + hwb);
    float4* dst = reinterpret_cast<float4*>(&a_lds[0][0]);
    #pragma unroll
    for (int it = 0; it < 16; it++) {
        int f = (it << 8) + tid;           // 0..4095 float4s
        int c = f >> 4, p4 = f & 15;
        dst[f] = src[(c << 10) + p4];
    }
    __syncthreads();

    int lane = tid & 63;
    int wv   = __builtin_amdgcn_readfirstlane(tid >> 6);   // wave-uniform wave id

    float nrm2 = 0.0f;
    for (int c = 0; c < C_; c++) {
        float a = a_lds[c][lane];
        nrm2 = fmaf(a, a, nrm2);
    }

    float bestv = -1e30f, secondv = -1e30f;
    int   besti = 0;
    for (int chunk = 0; chunk < 8; chunk++) {
        int kb = (wv << 8) + (chunk << 5);   // wave-uniform codeword base
        float acc[32];
        #pragma unroll
        for (int j = 0; j < 32; j++) acc[j] = 0.0f;
        for (int c = 0; c < C_; c++) {
            float a = a_lds[c][lane];
            const float4* wr = reinterpret_cast<const float4*>(wT + (c << 10) + kb);
            #pragma unroll
            for (int j4 = 0; j4 < 8; j4++) {
                float4 q = wr[j4];
                acc[j4 * 4 + 0] = fmaf(a, q.x, acc[j4 * 4 + 0]);
                acc[j4 * 4 + 1] = fmaf(a, q.y, acc[j4 * 4 + 1]);
                acc[j4 * 4 + 2] = fmaf(a, q.z, acc[j4 * 4 + 2]);
                acc[j4 * 4 + 3] = fmaf(a, q.w, acc[j4 * 4 + 3]);
            }
        }
        #pragma unroll
        for (int j = 0; j < 32; j++) {
            float v = acc[j];
            if (v > bestv)        { secondv = bestv; bestv = v; besti = kb + j; }
            else if (v > secondv) { secondv = v; }
        }
    }
    m_v[wv][lane] = bestv;
    m_s[wv][lane] = secondv;
    m_i[wv][lane] = besti;
    __syncthreads();

    int pix = lane;
    float bv = -1e30f, sv = -1e30f;
    int bi = 0;
    #pragma unroll
    for (int w = 0; w < 4; w++) {
        float v = m_v[w][pix];
        float s = m_s[w][pix];
        int   i = m_i[w][pix];
        if (v > bv) { sv = fmaxf(bv, s); bv = v; bi = i; }
        else        { sv = fmaxf(sv, v); }
    }

    // z_q write: thread group g covers channels g, g+4, ... (coalesced stores)
    int g = tid >> 6;
    size_t obase = ((size_t)b << 20) + (size_t)hwb + (size_t)pix;
    for (int c = g; c < C_; c += 4) {
        out[obase + ((size_t)c << 12)] = wT[(c << 10) + bi];
    }

    if (tid < 64) {
        int n = (b << 12) + hwb + pix;      // global flat BHW pixel index
        int fi = bi;
        if (bv - sv < REFINE_TAU) fi += MARK;   // tag near-ties for the np-emulation pass
        out[IDX_OFF + n] = (float)fi;
        float rinv = 1.0f / fmaxf(sqrtf(nrm2), 1e-12f);
        float d = 2.0f - 2.0f * bv * rinv;
        float dsum = d;
        for (int off = 32; off > 0; off >>= 1) dsum += __shfl_xor(dsum, off);
        if (lane == 0) atomicAdd(out + VQ_OFF, dsum * VQ_SCALE);
    }
}

// numpy-fp32-emulation re-rank for marked near-tie pixels.
// Reproduces: flat = fl32(z/np_norm), s = fp32 seq-FMA dot, d = fl32(2 - 2*s),
// argmin d with lowest-index ties (including the 2-2s ulp-collapse behavior).
// 128 blocks; block B owns pixels [B*1024,(B+1)*1024) -- no cross-block races.
__global__ __launch_bounds__(256)
void k_refine(const float* __restrict__ z, const float* __restrict__ wT,
              float* __restrict__ out) {
    __shared__ float fl[C_];
    __shared__ float rv[256];
    __shared__ int   rk[256];
    __shared__ int   q[QCAP];
    __shared__ int   qn;
    __shared__ float nrm_sh;
    int tid = threadIdx.x;
    int base = blockIdx.x << 10;
    if (tid == 0) qn = 0;
    __syncthreads();
    #pragma unroll
    for (int i = 0; i < 4; i++) {
        int n = base + (i << 8) + tid;
        if (out[IDX_OFF + n] >= (float)MARK) {
            int p = atomicAdd(&qn, 1);
            if (p < QCAP) q[p] = n;
        }
    }
    __syncthreads();
    int cnt = qn < QCAP ? qn : QCAP;

    for (int f = 0; f < cnt; f++) {
        int n = q[f];
        int b = n >> 12, hw = n & 4095;
        int kold = (int)out[IDX_OFF + n] - MARK;   // read BEFORE any patch write
        __syncthreads();
        fl[tid] = z[((size_t)((b << 8) + tid) << 12) + hw];
        __syncthreads();
        if (tid == 0) nrm_sh = fmaxf(np_norm256(fl), 1e-12f);
        __syncthreads();
        float fv = fl[tid] / nrm_sh;               // fl32 flat, like numpy
        __syncthreads();
        fl[tid] = fv;
        __syncthreads();

        // thread t ranks k = t, t+256, t+512, t+768 (coalesced wT column reads)
        float a0 = 0.f, a1 = 0.f, a2 = 0.f, a3 = 0.f;
        for (int c = 0; c < C_; c++) {
            float a = fl[c];                        // wave-uniform LDS broadcast
            const float* col = wT + (c << 10) + tid;
            a0 = fmaf(a, col[0],   a0);
            a1 = fmaf(a, col[256], a1);
            a2 = fmaf(a, col[512], a2);
            a3 = fmaf(a, col[768], a3);
        }
        float dbest = 1e30f; int kbest = 0;
        { float d = 2.0f - 2.0f * a0; if (d < dbest) { dbest = d; kbest = tid;       } }
        { float d = 2.0f - 2.0f * a1; if (d < dbest) { dbest = d; kbest = tid + 256; } }
        { float d = 2.0f - 2.0f * a2; if (d < dbest) { dbest = d; kbest = tid + 512; } }
        { float d = 2.0f - 2.0f * a3; if (d < dbest) { dbest = d; kbest = tid + 768; } }
        rv[tid] = dbest; rk[tid] = kbest;
        __syncthreads();
        for (int s = 128; s > 0; s >>= 1) {
            if (tid < s) {
                if (rv[tid + s] < rv[tid] ||
                    (rv[tid + s] == rv[tid] && rk[tid + s] < rk[tid])) {
                    rv[tid] = rv[tid + s];
                    rk[tid] = rk[tid + s];
                }
            }
            __syncthreads();
        }
        int knew = rk[0];
        if (tid == 0) out[IDX_OFF + n] = (float)knew;   // clears marker
        if (knew != kold) {
            out[((size_t)((b << 8) + tid) << 12) + hw] = wT[(tid << 10) + knew];
            if (tid == 0) {
                float ao = 0.f, an = 0.f;
                for (int c = 0; c < C_; c++) {
                    ao = fmaf(fl[c], wT[(c << 10) + kold], ao);
                    an = fmaf(fl[c], wT[(c << 10) + knew], an);
                }
                float d_old = 2.0f - 2.0f * ao;
                float d_new = 2.0f - 2.0f * an;
                atomicAdd(out + VQ_OFF, (d_new - d_old) * VQ_SCALE);
            }
        }
        __syncthreads();
    }
}

extern "C" void kernel_launch(void* const* d_in, const int* in_sizes, int n_in,
                              void* d_out, int out_size, void* d_ws, size_t ws_size,
                              hipStream_t stream) {
    const float* z = (const float*)d_in[0];   // (32,256,64,64) fp32
    const float* w = (const float*)d_in[1];   // (1024,256) fp32
    float* out = (float*)d_out;
    float* wT  = (float*)d_ws;                // 256*1024 floats = 1 MB of d_ws

    hipLaunchKernelGGL(k_init,   dim3(1),    dim3(64),  0, stream, out);
    hipLaunchKernelGGL(k_normw,  dim3(4),    dim3(256), 0, stream, w, wT);
    hipLaunchKernelGGL(k_topo,   dim3(256),  dim3(256), 0, stream, wT, out);
    hipLaunchKernelGGL(k_main,   dim3(2048), dim3(256), 0, stream, z, wT, out);
    hipLaunchKernelGGL(k_refine, dim3(128),  dim3(256), 0, stream, z, wT, out);
}

// Round 6
// 1452.374 us; speedup vs baseline: 1.4034x; 1.4034x over previous
//
#include <hip/hip_runtime.h>
#include <cstdint>
#include <cstddef>

// Problem constants
#define C_ 256
#define HW_ 4096
#define N_ 131072          // B*H*W = 32*64*64
#define K_ 1024
#define VQ_OFF   33554432  // after z_q (32*256*64*64)
#define IDX_OFF  33554433
#define TOPO_OFF 33685505  // IDX_OFF + 131072
#define VQ_SCALE (1.25f / 33554432.0f)   // (1+0.25) * mean over B*H*W*C elements
#define REFINE_TAU 4e-3f   // unnormalized-dot gap below which we np-emulate (round-3 proven)
#define MARK 2048          // idx marker for flagged pixels (true idx < 1024)
#define QCAP 256

// fp32 multiply with an anti-contraction barrier: numpy rounds x*x BEFORE the
// pairwise add; fp-contract would fuse mul+add into fma (different rounding).
__device__ __forceinline__ float mul_nofuse(float a, float b) {
    float t = a * b;
    asm volatile("" : "+v"(t));
    return t;
}

// numpy pairwise_sum of squares, n=128 (8-accumulator unroll, numpy combine order)
__device__ __forceinline__ float np_sumsq128(const float* x) {
    float r[8];
    #pragma unroll
    for (int j = 0; j < 8; j++) r[j] = mul_nofuse(x[j], x[j]);
    for (int i = 8; i < 128; i += 8) {
        #pragma unroll
        for (int j = 0; j < 8; j++) r[j] += mul_nofuse(x[i + j], x[i + j]);
    }
    return ((r[0] + r[1]) + (r[2] + r[3])) + ((r[4] + r[5]) + (r[6] + r[7]));
}

__device__ __forceinline__ float np_norm256(const float* x) {
    float ss = np_sumsq128(x) + np_sumsq128(x + 128);
    return sqrtf(ss);
}

__global__ void k_init(float* __restrict__ out) {
    if (threadIdx.x == 0) {
        out[VQ_OFF] = 0.0f;
        out[TOPO_OFF] = 0.0f;
    }
}

// Normalize codebook rows (numpy-emulated norms, true division) -> wT[c][k].
// 16 blocks x 256 threads; block handles 64 rows, LDS-staged, coalesced I/O.
__global__ __launch_bounds__(256)
void k_normw(const float* __restrict__ w, float* __restrict__ wT) {
    __shared__ float lw[64][257];
    __shared__ float nrm_sh[64];
    int tid = threadIdx.x;
    int r0 = blockIdx.x << 6;
    #pragma unroll
    for (int it = 0; it < 64; it++) {
        int f = (it << 8) + tid;       // 0..16383
        int row = f >> 8, c = f & 255;
        lw[row][c] = w[((size_t)(r0 + row) << 8) + c];
    }
    __syncthreads();
    if (tid < 64) nrm_sh[tid] = fmaxf(np_norm256(&lw[tid][0]), 1e-12f);
    __syncthreads();
    int rr = tid & 63, cg = tid >> 6;
    float nrm = nrm_sh[rr];
    for (int c = cg; c < C_; c += 4) {
        wT[(c << 10) + r0 + rr] = lw[rr][c] / nrm;
    }
}

// Topology smoothness loss over the 32x32 grid of normalized codewords.
__global__ void k_topo(const float* __restrict__ wT, float* __restrict__ out) {
    const float W12 = 0.35f / (32.0f * 31.0f * 256.0f);
    const float W34 = 0.35f / (32.0f * 256.0f);
    float acc = 0.0f;
    int base = (blockIdx.x << 8) + threadIdx.x;
    #pragma unroll
    for (int i = 0; i < 4; i++) {
        int e = base + (i << 16);      // e = c*1024 + k, coalesced over wT
        int k = e & 1023;
        int ii = k >> 5, jj = k & 31;
        float v = wT[e];
        if (jj < 31)  { float d = wT[e + 1]   - v; acc += d * d * W12; }
        if (ii < 31)  { float d = wT[e + 32]  - v; acc += d * d * W12; }
        if (jj == 31) { float d = wT[e - 31]  - v; acc += d * d * W34; }
        if (ii == 31) { float d = wT[e - 992] - v; acc += d * d * W34; }
    }
    for (int off = 32; off > 0; off >>= 1) acc += __shfl_xor(acc, off);
    __shared__ float red[4];
    if ((threadIdx.x & 63) == 0) red[threadIdx.x >> 6] = acc;
    __syncthreads();
    if (threadIdx.x == 0) atomicAdd(out + TOPO_OFF, red[0] + red[1] + red[2] + red[3]);
}

// Main: LDS-tiled register GEMM. Block = 64 pixels x 1024 codewords.
// kc (4 chunks of 256 k) outer; cc (8 chunks of 32 c) inner; per-thread 4x16 tile.
__global__ __launch_bounds__(256, 3)
void k_main(const float* __restrict__ z, const float* __restrict__ wT,
            float* __restrict__ out) {
    __shared__ float b_sh[32][256];    // 32 KB: B tile (c x k)
    __shared__ float a_sh[32][64];     // 8 KB: A tile (c x pix)
    __shared__ float nrm_sh[64];
    __shared__ int   bi_sh[64];

    // epilogue arrays alias b_sh (compute is done by then)
    float* eb = &b_sh[0][0];
    float (*mv)[17] = reinterpret_cast<float(*)[17]>(eb);
    float (*ms)[17] = reinterpret_cast<float(*)[17]>(eb + 64 * 17);
    int   (*mi)[17] = reinterpret_cast<int  (*)[17]>(eb + 128 * 17);

    int tid = threadIdx.x;
    int tx = tid & 15, ty = tid >> 4;
    int b   = blockIdx.x >> 6;
    int hwb = (blockIdx.x & 63) << 6;

    if (tid < 64) nrm_sh[tid] = 0.0f;

    const float* zb = z + ((size_t)b << 20) + hwb;

    float bv[4], sv[4];
    int   bix[4];
    #pragma unroll
    for (int m = 0; m < 4; m++) { bv[m] = -1e30f; sv[m] = -1e30f; bix[m] = 0; }

    for (int kc = 0; kc < 4; kc++) {
        float acc[4][16];
        #pragma unroll
        for (int m = 0; m < 4; m++)
            #pragma unroll
            for (int n = 0; n < 16; n++) acc[m][n] = 0.0f;

        for (int cc = 0; cc < 8; cc++) {
            __syncthreads();   // previous tile fully consumed
            // stage A: 32 c x 64 pix (512 float4, 2/thread), coalesced
            {
                const float4* srcA = reinterpret_cast<const float4*>(zb + (size_t)(cc << 5) * HW_);
                #pragma unroll
                for (int it = 0; it < 2; it++) {
                    int f = (it << 8) + tid;           // 0..511
                    int c = f >> 4, p4 = f & 15;
                    float4 v = srcA[c * 1024 + p4];
                    *reinterpret_cast<float4*>(&a_sh[c][p4 << 2]) = v;
                    if (kc == 0) {                      // accumulate ||z||^2 once
                        int p = p4 << 2;
                        atomicAdd(&nrm_sh[p + 0], v.x * v.x);
                        atomicAdd(&nrm_sh[p + 1], v.y * v.y);
                        atomicAdd(&nrm_sh[p + 2], v.z * v.z);
                        atomicAdd(&nrm_sh[p + 3], v.w * v.w);
                    }
                }
            }
            // stage B: 32 c x 256 k = 2048 float4, 8/thread, coalesced
            {
                const float4* srcB = reinterpret_cast<const float4*>(
                    wT + (size_t)(cc << 5) * K_ + (kc << 8));
                #pragma unroll
                for (int it = 0; it < 8; it++) {
                    int f = (it << 8) + tid;           // 0..2047
                    int c = f >> 6, k4 = f & 63;
                    *reinterpret_cast<float4*>(&b_sh[c][k4 << 2]) = srcB[c * 256 + k4];
                }
            }
            __syncthreads();

            // compute: per c-step, 5 ds_read_b128 + 64 FMA per lane
            #pragma unroll 2
            for (int c = 0; c < 32; c++) {
                float4 a4 = *reinterpret_cast<const float4*>(&a_sh[c][ty << 2]);
                const float* br = &b_sh[c][tx << 2];
                #pragma unroll
                for (int j = 0; j < 4; j++) {
                    float4 q = *reinterpret_cast<const float4*>(br + (j << 6));
                    #pragma unroll
                    for (int m = 0; m < 4; m++) {
                        float a = (m == 0) ? a4.x : (m == 1) ? a4.y : (m == 2) ? a4.z : a4.w;
                        acc[m][(j << 2) + 0] = fmaf(a, q.x, acc[m][(j << 2) + 0]);
                        acc[m][(j << 2) + 1] = fmaf(a, q.y, acc[m][(j << 2) + 1]);
                        acc[m][(j << 2) + 2] = fmaf(a, q.z, acc[m][(j << 2) + 2]);
                        acc[m][(j << 2) + 3] = fmaf(a, q.w, acc[m][(j << 2) + 3]);
                    }
                }
            }
        }
        // fold this kc's 16 sims/pixel into per-thread top-2
        #pragma unroll
        for (int m = 0; m < 4; m++) {
            #pragma unroll
            for (int j = 0; j < 4; j++) {
                #pragma unroll
                for (int i = 0; i < 4; i++) {
                    float v = acc[m][(j << 2) + i];
                    int   k = (kc << 8) + (j << 6) + (tx << 2) + i;
                    if (v > bv[m])      { sv[m] = bv[m]; bv[m] = v; bix[m] = k; }
                    else if (v > sv[m]) { sv[m] = v; }
                }
            }
        }
    }
    __syncthreads();   // done reading b_sh; safe to alias with epilogue arrays

    #pragma unroll
    for (int m = 0; m < 4; m++) {
        int p = (ty << 2) + m;
        mv[p][tx] = bv[m];
        ms[p][tx] = sv[m];
        mi[p][tx] = bix[m];
    }
    __syncthreads();

    if (tid < 64) {
        int p = tid;
        float BV = -1e30f, SV = -1e30f;
        int BI = 0;
        #pragma unroll
        for (int t = 0; t < 16; t++) {
            float v = mv[p][t];
            float s = ms[p][t];
            int   i = mi[p][t];
            if (v > BV)              { SV = fmaxf(BV, s); BV = v; BI = i; }
            else {
                if (v == BV && i < BI) BI = i;   // lowest index wins ties (argmin rule)
                SV = fmaxf(SV, v);
            }
        }
        bi_sh[p] = BI;
        int n = (b << 12) + hwb + p;
        int fi = BI;
        if (BV - SV < REFINE_TAU) fi += MARK;   // near-tie: np-emulation refine
        out[IDX_OFF + n] = (float)fi;
        float rinv = 1.0f / fmaxf(sqrtf(nrm_sh[p]), 1e-12f);
        float d = 2.0f - 2.0f * BV * rinv;
        float dsum = d;
        for (int off = 32; off > 0; off >>= 1) dsum += __shfl_xor(dsum, off);
        if (p == 0) atomicAdd(out + VQ_OFF, dsum * VQ_SCALE);
    }
    __syncthreads();

    // z_q write: group g covers channels g, g+4, ... (64-wide coalesced stores)
    int g = tid >> 6, pix = tid & 63;
    int bi = bi_sh[pix];
    size_t obase = ((size_t)b << 20) + (size_t)hwb + (size_t)pix;
    for (int c = g; c < C_; c += 4) {
        out[obase + ((size_t)c << 12)] = wT[(c << 10) + bi];
    }
}

// numpy-fp32-emulation re-rank for marked near-tie pixels (round-3 proven math).
// 256 blocks; block B owns pixels [B*512,(B+1)*512) -- no cross-block races.
__global__ __launch_bounds__(256)
void k_refine(const float* __restrict__ z, const float* __restrict__ wT,
              float* __restrict__ out) {
    __shared__ float fl[C_];
    __shared__ float rv[256];
    __shared__ int   rk[256];
    __shared__ int   q[QCAP];
    __shared__ int   qn;
    __shared__ float nrm_sh;
    int tid = threadIdx.x;
    int base = blockIdx.x << 9;
    if (tid == 0) qn = 0;
    __syncthreads();
    #pragma unroll
    for (int i = 0; i < 2; i++) {
        int n = base + (i << 8) + tid;
        if (out[IDX_OFF + n] >= (float)MARK) {
            int p = atomicAdd(&qn, 1);
            if (p < QCAP) q[p] = n;
        }
    }
    __syncthreads();
    int cnt = qn < QCAP ? qn : QCAP;

    for (int f = 0; f < cnt; f++) {
        int n = q[f];
        int b = n >> 12, hw = n & 4095;
        int kold = (int)out[IDX_OFF + n] - MARK;   // read BEFORE any patch write
        __syncthreads();
        fl[tid] = z[((size_t)((b << 8) + tid) << 12) + hw];
        __syncthreads();
        if (tid == 0) nrm_sh = fmaxf(np_norm256(fl), 1e-12f);
        __syncthreads();
        float fv = fl[tid] / nrm_sh;               // fl32 flat, like numpy
        __syncthreads();
        fl[tid] = fv;
        __syncthreads();

        // thread t ranks k = t, t+256, t+512, t+768 (coalesced wT column reads)
        float a0 = 0.f, a1 = 0.f, a2 = 0.f, a3 = 0.f;
        for (int c = 0; c < C_; c++) {
            float a = fl[c];
            const float* col = wT + (c << 10) + tid;
            a0 = fmaf(a, col[0],   a0);
            a1 = fmaf(a, col[256], a1);
            a2 = fmaf(a, col[512], a2);
            a3 = fmaf(a, col[768], a3);
        }
        float dbest = 1e30f; int kbest = 0;
        { float d = 2.0f - 2.0f * a0; if (d < dbest) { dbest = d; kbest = tid;       } }
        { float d = 2.0f - 2.0f * a1; if (d < dbest) { dbest = d; kbest = tid + 256; } }
        { float d = 2.0f - 2.0f * a2; if (d < dbest) { dbest = d; kbest = tid + 512; } }
        { float d = 2.0f - 2.0f * a3; if (d < dbest) { dbest = d; kbest = tid + 768; } }
        rv[tid] = dbest; rk[tid] = kbest;
        __syncthreads();
        for (int s = 128; s > 0; s >>= 1) {
            if (tid < s) {
                if (rv[tid + s] < rv[tid] ||
                    (rv[tid + s] == rv[tid] && rk[tid + s] < rk[tid])) {
                    rv[tid] = rv[tid + s];
                    rk[tid] = rk[tid + s];
                }
            }
            __syncthreads();
        }
        int knew = rk[0];
        if (tid == 0) out[IDX_OFF + n] = (float)knew;   // clears marker
        if (knew != kold) {
            out[((size_t)((b << 8) + tid) << 12) + hw] = wT[(tid << 10) + knew];
            if (tid == 0) {
                float ao = 0.f, an = 0.f;
                for (int c = 0; c < C_; c++) {
                    ao = fmaf(fl[c], wT[(c << 10) + kold], ao);
                    an = fmaf(fl[c], wT[(c << 10) + knew], an);
                }
                atomicAdd(out + VQ_OFF, ((2.0f - 2.0f * an) - (2.0f - 2.0f * ao)) * VQ_SCALE);
            }
        }
        __syncthreads();
    }
}

extern "C" void kernel_launch(void* const* d_in, const int* in_sizes, int n_in,
                              void* d_out, int out_size, void* d_ws, size_t ws_size,
                              hipStream_t stream) {
    const float* z = (const float*)d_in[0];   // (32,256,64,64) fp32
    const float* w = (const float*)d_in[1];   // (1024,256) fp32
    float* out = (float*)d_out;
    float* wT  = (float*)d_ws;                // 256*1024 floats = 1 MB of d_ws

    hipLaunchKernelGGL(k_init,   dim3(1),    dim3(64),  0, stream, out);
    hipLaunchKernelGGL(k_normw,  dim3(16),   dim3(256), 0, stream, w, wT);
    hipLaunchKernelGGL(k_topo,   dim3(256),  dim3(256), 0, stream, wT, out);
    hipLaunchKernelGGL(k_main,   dim3(2048), dim3(256), 0, stream, z, wT, out);
    hipLaunchKernelGGL(k_refine, dim3(256),  dim3(256), 0, stream, z, wT, out);
}

// Round 7
// 1402.573 us; speedup vs baseline: 1.4533x; 1.0355x over previous
//
#include <hip/hip_runtime.h>
#include <cstdint>
#include <cstddef>

// Problem constants
#define C_ 256
#define HW_ 4096
#define N_ 131072          // B*H*W = 32*64*64
#define K_ 1024
#define VQ_OFF   33554432  // after z_q (32*256*64*64)
#define IDX_OFF  33554433
#define TOPO_OFF 33685505  // IDX_OFF + 131072
#define VQ_SCALE (1.25f / 33554432.0f)   // (1+0.25) * mean over B*H*W*C elements
#define REFINE_TAU 4e-3f   // unnormalized-dot gap below which we np-emulate (round-3 proven)
#define MARK 2048          // idx marker for flagged pixels (true idx < 1024)
#define QCAP 256

// fp32 multiply with an anti-contraction barrier: numpy rounds x*x BEFORE the
// pairwise add; fp-contract would fuse mul+add into fma (different rounding).
__device__ __forceinline__ float mul_nofuse(float a, float b) {
    float t = a * b;
    asm volatile("" : "+v"(t));
    return t;
}

// numpy pairwise_sum of squares, n=128 (8-accumulator unroll, numpy combine order)
__device__ __forceinline__ float np_sumsq128(const float* x) {
    float r[8];
    #pragma unroll
    for (int j = 0; j < 8; j++) r[j] = mul_nofuse(x[j], x[j]);
    for (int i = 8; i < 128; i += 8) {
        #pragma unroll
        for (int j = 0; j < 8; j++) r[j] += mul_nofuse(x[i + j], x[i + j]);
    }
    return ((r[0] + r[1]) + (r[2] + r[3])) + ((r[4] + r[5]) + (r[6] + r[7]));
}

__device__ __forceinline__ float np_norm256(const float* x) {
    float ss = np_sumsq128(x) + np_sumsq128(x + 128);
    return sqrtf(ss);
}

// Normalize codebook rows (numpy-emulated norms, true division) -> wT[c][k].
// Also zero-inits the loss scalars (k_init folded in; later kernels are
// stream-ordered after this one).
__global__ __launch_bounds__(256)
void k_normw(const float* __restrict__ w, float* __restrict__ wT,
             float* __restrict__ out) {
    __shared__ float lw[64][257];
    __shared__ float nrm_sh[64];
    int tid = threadIdx.x;
    if (blockIdx.x == 0 && tid == 0) {
        out[VQ_OFF] = 0.0f;
        out[TOPO_OFF] = 0.0f;
    }
    int r0 = blockIdx.x << 6;
    #pragma unroll
    for (int it = 0; it < 64; it++) {
        int f = (it << 8) + tid;       // 0..16383
        int row = f >> 8, c = f & 255;
        lw[row][c] = w[((size_t)(r0 + row) << 8) + c];
    }
    __syncthreads();
    if (tid < 64) nrm_sh[tid] = fmaxf(np_norm256(&lw[tid][0]), 1e-12f);
    __syncthreads();
    int rr = tid & 63, cg = tid >> 6;
    float nrm = nrm_sh[rr];
    for (int c = cg; c < C_; c += 4) {
        wT[(c << 10) + r0 + rr] = lw[rr][c] / nrm;
    }
}

// Topology smoothness loss over the 32x32 grid of normalized codewords.
__global__ void k_topo(const float* __restrict__ wT, float* __restrict__ out) {
    const float W12 = 0.35f / (32.0f * 31.0f * 256.0f);
    const float W34 = 0.35f / (32.0f * 256.0f);
    float acc = 0.0f;
    int base = (blockIdx.x << 8) + threadIdx.x;
    #pragma unroll
    for (int i = 0; i < 4; i++) {
        int e = base + (i << 16);      // e = c*1024 + k, coalesced over wT
        int k = e & 1023;
        int ii = k >> 5, jj = k & 31;
        float v = wT[e];
        if (jj < 31)  { float d = wT[e + 1]   - v; acc += d * d * W12; }
        if (ii < 31)  { float d = wT[e + 32]  - v; acc += d * d * W12; }
        if (jj == 31) { float d = wT[e - 31]  - v; acc += d * d * W34; }
        if (ii == 31) { float d = wT[e - 992] - v; acc += d * d * W34; }
    }
    for (int off = 32; off > 0; off >>= 1) acc += __shfl_xor(acc, off);
    __shared__ float red[4];
    if ((threadIdx.x & 63) == 0) red[threadIdx.x >> 6] = acc;
    __syncthreads();
    if (threadIdx.x == 0) atomicAdd(out + TOPO_OFF, red[0] + red[1] + red[2] + red[3]);
}

// Main: LDS-tiled register GEMM. Block = 128 pixels x 1024 codewords.
// kc (4 chunks of 256 k) outer; cc (8 chunks of 32 c) inner; per-thread 8x16 tile.
// Thread (tx,ty): pixels ty*8..+7, codewords k = kc*256 + 4*tx + 64*j + i.
// LDS-vs-VALU per wave-c-step: 6 ds_read_b128 (72 cyc) / 128 FMA (64 VALU cyc)
// -> ratio 1.125 (was 1.875 with the 4x16 tile).
__global__ __launch_bounds__(256, 2)
void k_main(const float* __restrict__ z, const float* __restrict__ wT,
            float* __restrict__ out) {
    __shared__ float b_sh[32][256];    // 32 KB: B tile (c x k)
    __shared__ float a_sh[32][128];    // 16 KB: A tile (c x pix)
    __shared__ float nrm_sh[128];
    __shared__ int   bi_sh[128];

    // epilogue arrays alias b_sh (compute is done by then): 3 x 128 x 17 x 4B = 25.5 KB
    float* eb = &b_sh[0][0];
    float (*mv)[17] = reinterpret_cast<float(*)[17]>(eb);
    float (*ms)[17] = reinterpret_cast<float(*)[17]>(eb + 128 * 17);
    int   (*mi)[17] = reinterpret_cast<int  (*)[17]>(eb + 256 * 17);

    int tid = threadIdx.x;
    int tx = tid & 15, ty = tid >> 4;
    int b   = blockIdx.x >> 5;          // image index (32 pixel-blocks of 128 per image)
    int hwb = (blockIdx.x & 31) << 7;   // base flat hw within the 64x64 plane

    if (tid < 128) nrm_sh[tid] = 0.0f;

    const float* zb = z + ((size_t)b << 20) + hwb;

    float bv[8], sv[8];
    int   bix[8];
    #pragma unroll
    for (int m = 0; m < 8; m++) { bv[m] = -1e30f; sv[m] = -1e30f; bix[m] = 0; }

    for (int kc = 0; kc < 4; kc++) {
        float acc[8][16];
        #pragma unroll
        for (int m = 0; m < 8; m++)
            #pragma unroll
            for (int n = 0; n < 16; n++) acc[m][n] = 0.0f;

        for (int cc = 0; cc < 8; cc++) {
            __syncthreads();   // previous tile fully consumed
            // stage A: 32 c x 128 pix = 1024 float4, 4/thread, coalesced
            {
                const float4* srcA = reinterpret_cast<const float4*>(zb + (size_t)(cc << 5) * HW_);
                #pragma unroll
                for (int it = 0; it < 4; it++) {
                    int f = (it << 8) + tid;           // 0..1023
                    int c = f >> 5, p4 = f & 31;
                    float4 v = srcA[c * 1024 + p4];
                    *reinterpret_cast<float4*>(&a_sh[c][p4 << 2]) = v;
                    if (kc == 0) {                      // accumulate ||z||^2 once
                        int p = p4 << 2;
                        atomicAdd(&nrm_sh[p + 0], v.x * v.x);
                        atomicAdd(&nrm_sh[p + 1], v.y * v.y);
                        atomicAdd(&nrm_sh[p + 2], v.z * v.z);
                        atomicAdd(&nrm_sh[p + 3], v.w * v.w);
                    }
                }
            }
            // stage B: 32 c x 256 k = 2048 float4, 8/thread, coalesced
            {
                const float4* srcB = reinterpret_cast<const float4*>(
                    wT + (size_t)(cc << 5) * K_ + (kc << 8));
                #pragma unroll
                for (int it = 0; it < 8; it++) {
                    int f = (it << 8) + tid;           // 0..2047
                    int c = f >> 6, k4 = f & 63;
                    *reinterpret_cast<float4*>(&b_sh[c][k4 << 2]) = srcB[c * 256 + k4];
                }
            }
            __syncthreads();

            // compute: per c-step, 6 ds_read_b128 + 128 FMA per lane
            #pragma unroll 2
            for (int c = 0; c < 32; c++) {
                float4 A0 = *reinterpret_cast<const float4*>(&a_sh[c][ty << 3]);
                float4 A1 = *reinterpret_cast<const float4*>(&a_sh[c][(ty << 3) + 4]);
                float av[8] = {A0.x, A0.y, A0.z, A0.w, A1.x, A1.y, A1.z, A1.w};
                const float* br = &b_sh[c][tx << 2];
                #pragma unroll
                for (int j = 0; j < 4; j++) {
                    float4 q = *reinterpret_cast<const float4*>(br + (j << 6));
                    #pragma unroll
                    for (int m = 0; m < 8; m++) {
                        acc[m][(j << 2) + 0] = fmaf(av[m], q.x, acc[m][(j << 2) + 0]);
                        acc[m][(j << 2) + 1] = fmaf(av[m], q.y, acc[m][(j << 2) + 1]);
                        acc[m][(j << 2) + 2] = fmaf(av[m], q.z, acc[m][(j << 2) + 2]);
                        acc[m][(j << 2) + 3] = fmaf(av[m], q.w, acc[m][(j << 2) + 3]);
                    }
                }
            }
        }
        // fold this kc's 16 sims/pixel into per-thread top-2 (k ascending per thread)
        #pragma unroll
        for (int m = 0; m < 8; m++) {
            #pragma unroll
            for (int j = 0; j < 4; j++) {
                #pragma unroll
                for (int i = 0; i < 4; i++) {
                    float v = acc[m][(j << 2) + i];
                    int   k = (kc << 8) + (j << 6) + (tx << 2) + i;
                    if (v > bv[m])      { sv[m] = bv[m]; bv[m] = v; bix[m] = k; }
                    else if (v > sv[m]) { sv[m] = v; }
                }
            }
        }
    }
    __syncthreads();   // done reading b_sh; safe to alias with epilogue arrays

    #pragma unroll
    for (int m = 0; m < 8; m++) {
        int p = (ty << 3) + m;
        mv[p][tx] = bv[m];
        ms[p][tx] = sv[m];
        mi[p][tx] = bix[m];
    }
    __syncthreads();

    if (tid < 128) {
        int p = tid;
        float BV = -1e30f, SV = -1e30f;
        int BI = 0;
        #pragma unroll
        for (int t = 0; t < 16; t++) {
            float v = mv[p][t];
            float s = ms[p][t];
            int   i = mi[p][t];
            if (v > BV)              { SV = fmaxf(BV, s); BV = v; BI = i; }
            else {
                if (v == BV && i < BI) BI = i;   // lowest index wins ties (argmin rule)
                SV = fmaxf(SV, v);
            }
        }
        bi_sh[p] = BI;
        int n = (b << 12) + hwb + p;
        int fi = BI;
        if (BV - SV < REFINE_TAU) fi += MARK;   // near-tie: np-emulation refine
        out[IDX_OFF + n] = (float)fi;
        float rinv = 1.0f / fmaxf(sqrtf(nrm_sh[p]), 1e-12f);
        float d = 2.0f - 2.0f * BV * rinv;
        float dsum = d;
        for (int off = 32; off > 0; off >>= 1) dsum += __shfl_xor(dsum, off);
        if ((tid & 63) == 0) atomicAdd(out + VQ_OFF, dsum * VQ_SCALE);
    }
    __syncthreads();

    // z_q write: group g covers channels g, g+2, ... (128-wide coalesced stores)
    int g = tid >> 7, pix = tid & 127;
    int bi = bi_sh[pix];
    size_t obase = ((size_t)b << 20) + (size_t)hwb + (size_t)pix;
    for (int c = g; c < C_; c += 2) {
        out[obase + ((size_t)c << 12)] = wT[(c << 10) + bi];
    }
}

// numpy-fp32-emulation re-rank for marked near-tie pixels (round-3 proven math).
// 256 blocks; block B owns pixels [B*512,(B+1)*512) -- no cross-block races.
__global__ __launch_bounds__(256)
void k_refine(const float* __restrict__ z, const float* __restrict__ wT,
              float* __restrict__ out) {
    __shared__ float fl[C_];
    __shared__ float rv[256];
    __shared__ int   rk[256];
    __shared__ int   q[QCAP];
    __shared__ int   qn;
    __shared__ float nrm_sh;
    int tid = threadIdx.x;
    int base = blockIdx.x << 9;
    if (tid == 0) qn = 0;
    __syncthreads();
    #pragma unroll
    for (int i = 0; i < 2; i++) {
        int n = base + (i << 8) + tid;
        if (out[IDX_OFF + n] >= (float)MARK) {
            int p = atomicAdd(&qn, 1);
            if (p < QCAP) q[p] = n;
        }
    }
    __syncthreads();
    int cnt = qn < QCAP ? qn : QCAP;

    for (int f = 0; f < cnt; f++) {
        int n = q[f];
        int b = n >> 12, hw = n & 4095;
        int kold = (int)out[IDX_OFF + n] - MARK;   // read BEFORE any patch write
        __syncthreads();
        fl[tid] = z[((size_t)((b << 8) + tid) << 12) + hw];
        __syncthreads();
        if (tid == 0) nrm_sh = fmaxf(np_norm256(fl), 1e-12f);
        __syncthreads();
        float fv = fl[tid] / nrm_sh;               // fl32 flat, like numpy
        __syncthreads();
        fl[tid] = fv;
        __syncthreads();

        // thread t ranks k = t, t+256, t+512, t+768 (coalesced wT column reads)
        float a0 = 0.f, a1 = 0.f, a2 = 0.f, a3 = 0.f;
        for (int c = 0; c < C_; c++) {
            float a = fl[c];
            const float* col = wT + (c << 10) + tid;
            a0 = fmaf(a, col[0],   a0);
            a1 = fmaf(a, col[256], a1);
            a2 = fmaf(a, col[512], a2);
            a3 = fmaf(a, col[768], a3);
        }
        float dbest = 1e30f; int kbest = 0;
        { float d = 2.0f - 2.0f * a0; if (d < dbest) { dbest = d; kbest = tid;       } }
        { float d = 2.0f - 2.0f * a1; if (d < dbest) { dbest = d; kbest = tid + 256; } }
        { float d = 2.0f - 2.0f * a2; if (d < dbest) { dbest = d; kbest = tid + 512; } }
        { float d = 2.0f - 2.0f * a3; if (d < dbest) { dbest = d; kbest = tid + 768; } }
        rv[tid] = dbest; rk[tid] = kbest;
        __syncthreads();
        for (int s = 128; s > 0; s >>= 1) {
            if (tid < s) {
                if (rv[tid + s] < rv[tid] ||
                    (rv[tid + s] == rv[tid] && rk[tid + s] < rk[tid])) {
                    rv[tid] = rv[tid + s];
                    rk[tid] = rk[tid + s];
                }
            }
            __syncthreads();
        }
        int knew = rk[0];
        if (tid == 0) out[IDX_OFF + n] = (float)knew;   // clears marker
        if (knew != kold) {
            out[((size_t)((b << 8) + tid) << 12) + hw] = wT[(tid << 10) + knew];
            if (tid == 0) {
                float ao = 0.f, an = 0.f;
                for (int c = 0; c < C_; c++) {
                    ao = fmaf(fl[c], wT[(c << 10) + kold], ao);
                    an = fmaf(fl[c], wT[(c << 10) + knew], an);
                }
                atomicAdd(out + VQ_OFF, ((2.0f - 2.0f * an) - (2.0f - 2.0f * ao)) * VQ_SCALE);
            }
        }
        __syncthreads();
    }
}

extern "C" void kernel_launch(void* const* d_in, const int* in_sizes, int n_in,
                              void* d_out, int out_size, void* d_ws, size_t ws_size,
                              hipStream_t stream) {
    const float* z = (const float*)d_in[0];   // (32,256,64,64) fp32
    const float* w = (const float*)d_in[1];   // (1024,256) fp32
    float* out = (float*)d_out;
    float* wT  = (float*)d_ws;                // 256*1024 floats = 1 MB of d_ws

    hipLaunchKernelGGL(k_normw,  dim3(16),   dim3(256), 0, stream, w, wT, out);
    hipLaunchKernelGGL(k_topo,   dim3(256),  dim3(256), 0, stream, wT, out);
    hipLaunchKernelGGL(k_main,   dim3(1024), dim3(256), 0, stream, z, wT, out);
    hipLaunchKernelGGL(k_refine, dim3(256),  dim3(256), 0, stream, z, wT, out);
}